// Round 5
// baseline (3315.564 us; speedup 1.0000x reference)
//
#include <hip/hip_runtime.h>
#include <hip/hip_bf16.h>
#include <math.h>

#define NPRED 65536
#define NGT   128
#define NCLS  256
#define CAP   12288
#define VCAP  160
#define SENT_I 0x7FFFFFFF

// ---------- numeric helpers (match reference op order; no FMA contraction) ----------

__device__ __forceinline__ float sigmoid_f32(float x) {
#pragma clang fp contract(off)
    double s = 1.0 / (1.0 + exp(-(double)x));
    return (float)s;
}

__device__ __forceinline__ unsigned f2u(float f) {
    unsigned u = __float_as_uint(f);
    return (u & 0x80000000u) ? ~u : (u | 0x80000000u);
}

__device__ __forceinline__ float giou3d(
    float pl0, float pl1, float pl2, float ph0, float ph1, float ph2, float pvol,
    float gl0, float gl1, float gl2, float gh0, float gh1, float gh2, float gvol)
{
#pragma clang fp contract(off)
    float c0 = fmaxf(fminf(ph0, gh0) - fmaxf(pl0, gl0), 0.0f);
    float c1 = fmaxf(fminf(ph1, gh1) - fmaxf(pl1, gl1), 0.0f);
    float c2 = fmaxf(fminf(ph2, gh2) - fmaxf(pl2, gl2), 0.0f);
    float overlap = (c0 * c1) * c2;
    float uni = fmaxf((pvol + gvol) - overlap, 1e-6f);
    float iou = overlap / uni;
    float e0 = fmaxf(fmaxf(ph0, gh0) - fminf(pl0, gl0), 0.0f);
    float e1 = fmaxf(fmaxf(ph1, gh1) - fminf(pl1, gl1), 0.0f);
    float e2 = fmaxf(fmaxf(ph2, gh2) - fminf(pl2, gl2), 0.0f);
    float enc = fmaxf((e0 * e1) * e2, 1e-6f);
    return iou - (enc - uni) / enc;
}

// ---------- kernels ----------

__global__ void k_init(int* ccnt, unsigned* cmax) {
    int t = threadIdx.x;
    if (t < NGT) { ccnt[t] = 0; cmax[t] = 0u; }
}

__global__ __launch_bounds__(256) void k_cost(
    const float* __restrict__ pc, const float* __restrict__ ps,
    const float* __restrict__ cls, const float* __restrict__ gc,
    const float* __restrict__ gs, const int* __restrict__ lab,
    float* __restrict__ costT, int* __restrict__ ccnt, unsigned* __restrict__ cmax,
    int2* __restrict__ cpair)
{
#pragma clang fp contract(off)
    __shared__ float gb[NGT][6];
    __shared__ float gvol[NGT];
    __shared__ int   glab[NGT];
    int tid = threadIdx.x;
    if (tid < NGT) {
        float c0 = gc[tid * 3 + 0], c1 = gc[tid * 3 + 1], c2 = gc[tid * 3 + 2];
        float s0 = gs[tid * 3 + 0], s1 = gs[tid * 3 + 1], s2 = gs[tid * 3 + 2];
        float l0 = c0 - s0 / 2.0f, l1 = c1 - s1 / 2.0f, l2 = c2 - s2 / 2.0f;
        float h0 = c0 + s0 / 2.0f, h1 = c1 + s1 / 2.0f, h2 = c2 + s2 / 2.0f;
        gb[tid][0] = l0; gb[tid][1] = l1; gb[tid][2] = l2;
        gb[tid][3] = h0; gb[tid][4] = h1; gb[tid][5] = h2;
        gvol[tid] = ((h0 - l0) * (h1 - l1)) * (h2 - l2);
        glab[tid] = lab[tid];
    }
    __syncthreads();

    int p = blockIdx.x * 256 + tid;
    float c0 = pc[p * 3 + 0], c1 = pc[p * 3 + 1], c2 = pc[p * 3 + 2];
    float s0 = ps[p * 3 + 0], s1 = ps[p * 3 + 1], s2 = ps[p * 3 + 2];
    float pl0 = c0 - s0 / 2.0f, pl1 = c1 - s1 / 2.0f, pl2 = c2 - s2 / 2.0f;
    float ph0 = c0 + s0 / 2.0f, ph1 = c1 + s1 / 2.0f, ph2 = c2 + s2 / 2.0f;
    float pvol = ((ph0 - pl0) * (ph1 - pl1)) * (ph2 - pl2);
    const float* crow = cls + (size_t)p * NCLS;

    for (int g = 0; g < NGT; ++g) {
        float gio = giou3d(pl0, pl1, pl2, ph0, ph1, ph2, pvol,
                           gb[g][0], gb[g][1], gb[g][2], gb[g][3], gb[g][4], gb[g][5], gvol[g]);
        float m = gio;
        for (int off = 32; off; off >>= 1) m = fmaxf(m, __shfl_xor(m, off, 64));
        if ((tid & 63) == 0) atomicMax(&cmax[g], f2u(m));
        float sg = sigmoid_f32(crow[glab[g]]);
        float tot = (-sg) + (2.0f * (-gio));
        costT[(size_t)g * NPRED + p] = tot;
        if (gio > 0.25f) {
            int slot = atomicAdd(&ccnt[g], 1);
            if (slot < CAP) {
                cpair[(size_t)g * CAP + slot] = make_int2(p, __float_as_int(gio));
            }
        }
    }
}

__global__ __launch_bounds__(128) void k_sort(const unsigned* __restrict__ cmax,
                                              int* __restrict__ order) {
    __shared__ unsigned m[NGT];
    int t = threadIdx.x;
    m[t] = cmax[t];
    __syncthreads();
    unsigned mt = m[t];
    int r = 0;
    for (int k = 0; k < NGT; ++k) {
        unsigned mk = m[k];
        if (mk < mt || (mk == mt && k < t)) r++;
    }
    order[r] = t;
}

// per-(row,segment) min of raw cost, lex (value, index); also zero inVmap/failFlag
// GRID: 128 rows * 512 segs = 65536 waves = 16384 blocks of 4 waves
__global__ __launch_bounds__(256) void k_segmin(
    const float* __restrict__ costT, float* __restrict__ segval, int* __restrict__ segidx,
    int* __restrict__ inVmap, int* __restrict__ failFlag)
{
    int gid = blockIdx.x * 256 + threadIdx.x;
    if (gid < NPRED) inVmap[gid] = 0;
    if (gid == 0) *failFlag = 0;
    int wave = blockIdx.x * 4 + (threadIdx.x >> 6);
    int lane = threadIdx.x & 63;
    int row = wave >> 9;   // [0,128)
    int seg = wave & 511;  // [0,512)
    const float* crow = costT + (size_t)row * NPRED;
    int j0 = seg * 128 + lane;
    float c0 = crow[j0], c1 = crow[j0 + 64];
    float bc; int bj;
    if (c1 < c0) { bc = c1; bj = j0 + 64; } else { bc = c0; bj = j0; }
    for (int off = 1; off < 64; off <<= 1) {
        float oc = __shfl_xor(bc, off, 64);
        int   oj = __shfl_xor(bj, off, 64);
        if (oc < bc || (oc == bc && oj < bj)) { bc = oc; bj = oj; }
    }
    if (lane == 0) { segval[row * 512 + seg] = bc; segidx[row * 512 + seg] = bj; }
}

// sparse JV LSA with O(1) per-SR-row heads: per-row minima over untouched columns
// cached in LDS (rowmin*), repaired only when their argmin column joins V.
// Bit-identical to the dense numpy JV (monotone transform, lex tie-breaks).
__global__ __launch_bounds__(1024) void k_lsa_sparse(
    const float* __restrict__ costT,
    float* __restrict__ segval, int* __restrict__ segidx,
    int* __restrict__ inVmap, int* __restrict__ failFlag,
    unsigned* __restrict__ usedbits, int* __restrict__ out)
{
#pragma clang fp contract(off)
    __shared__ double u_l[NGT];
    __shared__ int    c4r[NGT];
    __shared__ float  rowminval[NGT];
    __shared__ int    rowminidx[NGT];
    __shared__ int    colidV[VCAP];
    __shared__ double vV[VCAP], shortV[VCAP];
    __shared__ int    pathV[VCAP], r4cV[VCAP];
    __shared__ unsigned char SCV[VCAP];
    __shared__ int    SRr[VCAP];
    __shared__ double headv[VCAP];
    __shared__ int    headj[VCAP];
    __shared__ double wvr[2]; __shared__ int wjr[2]; __shared__ int wkr[2];
    __shared__ int sh_bi, sh_sink, sh_nSR, sh_nV, sh_fixcol, sh_fail;
    __shared__ double sh_mv;

    int tid = threadIdx.x;
    int lane = tid & 63, wav = tid >> 6;

    if (tid < NGT) { u_l[tid] = 0.0; c4r[tid] = -1; }
    if (tid == 0) { sh_nV = 0; sh_fixcol = -1; sh_fail = 0; }
    // initial per-row min over all 512 segment minima (8 threads per row)
    {
        int r = tid >> 3, sub = tid & 7;
        float bc = INFINITY; int bj = SENT_I;
        for (int s0 = sub * 64; s0 < sub * 64 + 64; ++s0) {
            float c = segval[r * 512 + s0];
            int   j = segidx[r * 512 + s0];
            if (c < bc || (c == bc && j < bj)) { bc = c; bj = j; }
        }
        for (int off = 1; off < 8; off <<= 1) {
            float oc = __shfl_xor(bc, off, 64);
            int   oj = __shfl_xor(bj, off, 64);
            if (oc < bc || (oc == bc && oj < bj)) { bc = oc; bj = oj; }
        }
        if (sub == 0) { rowminval[r] = bc; rowminidx[r] = bj; }
    }
    __syncthreads();

    for (int cur = 0; cur < NGT; ++cur) {
        int fixcol = sh_fixcol;  // register copy; tid0 resets after barriers below
        // phase A: repair segment minima where the argmin was the column that joined V
        if (fixcol >= 0) {
            int seg = fixcol >> 7, base = seg << 7;
            int r = tid >> 3, sub = tid & 7;
            if (segidx[r * 512 + seg] == fixcol) {
                const float* crow = costT + (size_t)r * NPRED;
                float bc = INFINITY; int bj = SENT_I;
                for (int t = 0; t < 16; ++t) {
                    int j = base + sub * 16 + t;
                    if (inVmap[j] == 0) {
                        float c = crow[j];
                        if (c < bc || (c == bc && j < bj)) { bc = c; bj = j; }
                    }
                }
                for (int off = 1; off < 8; off <<= 1) {
                    float oc = __shfl_xor(bc, off, 64);
                    int   oj = __shfl_xor(bj, off, 64);
                    if (oc < bc || (oc == bc && oj < bj)) { bc = oc; bj = oj; }
                }
                if (sub == 0) { segval[r * 512 + seg] = bc; segidx[r * 512 + seg] = bj; }
            }
        }
        __syncthreads();
        // phase B: recompute rowmin for rows whose row-min pointed at fixcol
        if (fixcol >= 0) {
            int r = tid >> 3, sub = tid & 7;
            if (rowminidx[r] == fixcol) {
                float bc = INFINITY; int bj = SENT_I;
                for (int s0 = sub * 64; s0 < sub * 64 + 64; ++s0) {
                    float c = segval[r * 512 + s0];
                    int   j = segidx[r * 512 + s0];
                    if (c < bc || (c == bc && j < bj)) { bc = c; bj = j; }
                }
                for (int off = 1; off < 8; off <<= 1) {
                    float oc = __shfl_xor(bc, off, 64);
                    int   oj = __shfl_xor(bj, off, 64);
                    if (oc < bc || (oc == bc && oj < bj)) { bc = oc; bj = oj; }
                }
                if (sub == 0) { rowminval[r] = bc; rowminidx[r] = bj; }
            }
        }
        __syncthreads();
        // round init
        if (tid < sh_nV) { shortV[tid] = INFINITY; pathV[tid] = -1; SCV[tid] = 0; }
        if (tid == 0) {
            sh_bi = cur; sh_sink = -1; sh_mv = 0.0;
            SRr[0] = cur; sh_nSR = 1; sh_fixcol = -1;
            int hj = rowminidx[cur];
            headj[0] = hj;
            headv[0] = (hj == SENT_I) ? INFINITY
                                      : ((0.0 + (double)rowminval[cur]) - u_l[cur]);
        }
        __syncthreads();

        while (true) {
            int bi = sh_bi; double mv = sh_mv; int nV = sh_nV; int s = sh_nSR;
            double ui = u_l[bi];
            if (wav < 2) {
                // exact scan of V-members for the current row
                double bv = INFINITY; int bj = SENT_I, bk = -1;
                if (tid < nV && !SCV[tid]) {
                    double c = (double)costT[(size_t)bi * NPRED + colidV[tid]];
                    double r = ((mv + c) - ui) - vV[tid];
                    if (r < shortV[tid]) { shortV[tid] = r; pathV[tid] = bi; }
                    bv = shortV[tid]; bj = colidV[tid]; bk = tid;
                }
                for (int off = 1; off < 64; off <<= 1) {
                    double ov = __shfl_xor(bv, off, 64);
                    int    oj = __shfl_xor(bj, off, 64);
                    int    ok = __shfl_xor(bk, off, 64);
                    if (ov < bv || (ov == bv && oj < bj)) { bv = ov; bj = oj; bk = ok; }
                }
                if (lane == 0) { wvr[wav] = bv; wjr[wav] = bj; wkr[wav] = bk; }
            }
            __syncthreads();
            if (tid == 0) {
                double bv = wvr[0]; int bj = wjr[0], bk = wkr[0];
                if (wvr[1] < bv || (wvr[1] == bv && wjr[1] < bj)) { bv = wvr[1]; bj = wjr[1]; bk = wkr[1]; }
                int pick_row = -1;
                for (int p = 0; p < s; ++p) {  // ascending => earliest SR row kept on exact tie
                    if (headv[p] < bv || (headv[p] == bv && headj[p] < bj)) {
                        bv = headv[p]; bj = headj[p]; bk = -1; pick_row = SRr[p];
                    }
                }
                sh_mv = bv;
                if (bk >= 0) {
                    // assigned V-member: extend alternating path; head computed once (O(1))
                    SCV[bk] = 1;
                    int nr = r4cV[bk];
                    SRr[s] = nr;
                    int hj = rowminidx[nr];
                    headj[s] = hj;
                    headv[s] = (hj == SENT_I) ? INFINITY
                                              : ((bv + (double)rowminval[nr]) - u_l[nr]);
                    sh_nSR = s + 1; sh_bi = nr;
                } else {
                    // untouched column: always unassigned => sink; join V
                    int k2 = sh_nV;
                    if (k2 >= VCAP) { sh_fail = 1; }
                    else {
                        colidV[k2] = bj; vV[k2] = 0.0; shortV[k2] = bv;
                        pathV[k2] = pick_row; SCV[k2] = 1; r4cV[k2] = -1;
                        inVmap[bj] = k2 + 1;
                        sh_nV = k2 + 1;
                        sh_sink = bj; sh_fixcol = bj;
                    }
                }
            }
            __syncthreads();
            if (sh_sink >= 0 || sh_fail) break;
        }
        if (sh_fail) break;

        // round end: dual updates + augment
        double mvf = sh_mv;
        if (tid < sh_nV && SCV[tid]) vV[tid] -= (mvf - shortV[tid]);
        if (tid == 0) {
            u_l[cur] += mvf;
            int s = sh_nSR;
            for (int q = 1; q < s; ++q) {
                int i2 = SRr[q];
                int kk = inVmap[c4r[i2]] - 1;
                u_l[i2] += mvf - shortV[kk];
            }
            int j = sh_sink;
            while (true) {
                int kk = inVmap[j] - 1;
                int i2 = pathV[kk];
                r4cV[kk] = i2;
                int nj = c4r[i2];
                c4r[i2] = j;
                j = nj;
                if (i2 == cur) break;
            }
        }
        __syncthreads();
    }

    if (tid == 0 && sh_fail) *failFlag = 1;
    if (!sh_fail) {
        for (int w = tid; w < 2048; w += 1024) usedbits[w] = 0u;
        __syncthreads();
        if (tid < NGT) {
            int p = c4r[tid];
            atomicOr(&usedbits[p >> 5], 1u << (p & 31));
            out[tid]        = p;
            out[1408 + tid] = tid;
        }
    }
}

// dense fallback: only runs if k_lsa_sparse flagged overflow (should never happen)
__global__ __launch_bounds__(1024) void k_lsa_dense(
    const float* __restrict__ costT, const int* __restrict__ failFlag,
    double* __restrict__ v, double* __restrict__ shortest,
    int* __restrict__ path, int* __restrict__ row4col,
    unsigned char* __restrict__ SC, unsigned* __restrict__ usedbits,
    int* __restrict__ out)
{
#pragma clang fp contract(off)
    if (*failFlag == 0) return;
    __shared__ double u_l[NGT];
    __shared__ int    c4r[NGT];
    __shared__ int    SR[NGT + 1];
    __shared__ int    bi, bsink, nSR;
    __shared__ double bmin;
    __shared__ double wval[16];
    __shared__ int    widx[16];
    int tid = threadIdx.x;

    for (int j = tid; j < NPRED; j += 1024) { v[j] = 0.0; row4col[j] = -1; }
    if (tid < NGT) { u_l[tid] = 0.0; c4r[tid] = -1; }
    __syncthreads();

    for (int cur = 0; cur < NGT; ++cur) {
        for (int j = tid; j < NPRED; j += 1024) {
            shortest[j] = (double)INFINITY; path[j] = -1; SC[j] = 0;
        }
        if (tid == 0) { bi = cur; bsink = -1; bmin = 0.0; SR[0] = cur; nSR = 1; }
        __syncthreads();

        while (true) {
            int irow = bi;
            double mv = bmin;
            double ui = u_l[irow];
            const float* crow = costT + (size_t)irow * NPRED;
            double bestv = (double)INFINITY;
            int    bestj = SENT_I;
            for (int j = tid; j < NPRED; j += 1024) {
                if (!SC[j]) {
                    double s = shortest[j];
                    double r = ((mv + (double)crow[j]) - ui) - v[j];
                    if (r < s) { s = r; shortest[j] = r; path[j] = irow; }
                    if (s < bestv || (s == bestv && j < bestj)) { bestv = s; bestj = j; }
                }
            }
            for (int off = 32; off; off >>= 1) {
                double ov = __shfl_down(bestv, off, 64);
                int    oj = __shfl_down(bestj, off, 64);
                if (ov < bestv || (ov == bestv && oj < bestj)) { bestv = ov; bestj = oj; }
            }
            if ((tid & 63) == 0) { wval[tid >> 6] = bestv; widx[tid >> 6] = bestj; }
            __syncthreads();
            if (tid == 0) {
                double bv = wval[0]; int bj = widx[0];
                for (int w = 1; w < 16; ++w) {
                    double ov = wval[w]; int oj = widx[w];
                    if (ov < bv || (ov == bv && oj < bj)) { bv = ov; bj = oj; }
                }
                bmin = bv;
                SC[bj] = 1;
                int r = row4col[bj];
                if (r < 0) { bsink = bj; }
                else       { SR[nSR++] = r; bi = r; }
            }
            __syncthreads();
            if (bsink >= 0) break;
        }

        double mv = bmin;
        for (int j = tid; j < NPRED; j += 1024)
            if (SC[j]) v[j] -= (mv - shortest[j]);
        if (tid == 0) {
            u_l[cur] += mv;
            for (int k = 1; k < nSR; ++k) {
                int i2 = SR[k];
                u_l[i2] += mv - shortest[c4r[i2]];
            }
            int j = bsink;
            while (true) {
                int i2 = path[j];
                row4col[j] = i2;
                int nj = c4r[i2];
                c4r[i2] = j;
                j = nj;
                if (i2 == cur) break;
            }
        }
        __syncthreads();
    }

    for (int w = tid; w < 2048; w += 1024) usedbits[w] = 0u;
    __syncthreads();
    for (int j = tid; j < NPRED; j += 1024)
        if (row4col[j] >= 0) atomicOr(&usedbits[j >> 5], 1u << (j & 31));
    if (tid < NGT) {
        out[tid]        = c4r[tid];
        out[1408 + tid] = tid;
    }
}

// single-wave dynamic assignment: register top-10 per lane + shuffle extraction,
// used-set as LDS bitmap. No merge trees, no bank conflicts.
__global__ __launch_bounds__(64) void k_dyn(
    const int* __restrict__ order, const int* __restrict__ ccnt,
    const int2* __restrict__ cpair,
    const unsigned* __restrict__ usedbits_g, int* __restrict__ out)
{
    __shared__ unsigned bits[2048];
    int lane = threadIdx.x;
    for (int w = lane; w < 2048; w += 64) bits[w] = usedbits_g[w];
    __syncthreads();

    for (int k = 0; k < NGT; ++k) {
        int gt = order[k];
        int nc = ccnt[gt];
        if (nc > CAP) nc = CAP;

        float lv[10]; int li[10];
#pragma unroll
        for (int q = 0; q < 10; ++q) { lv[q] = -1e30f; li[q] = SENT_I; }

        for (int c = lane; c < nc; c += 64) {
            int2 pr = cpair[(size_t)gt * CAP + c];
            int p = pr.x;
            if (bits[p >> 5] & (1u << (p & 31))) continue;
            float cvv = __int_as_float(pr.y); int cii = p;
#pragma unroll
            for (int q = 0; q < 10; ++q) {
                bool b = (cvv > lv[q]) || (cvv == lv[q] && cii < li[q]);
                float tv = b ? lv[q] : cvv; int ti = b ? li[q] : cii;
                if (b) { lv[q] = cvv; li[q] = cii; }
                cvv = tv; cii = ti;
            }
        }

        // 10 extraction rounds: wave argmax by (val desc, idx asc); winner pops head
#pragma unroll
        for (int q = 0; q < 10; ++q) {
            float mo = lv[0]; int mj = li[0];
#pragma unroll
            for (int off = 1; off < 64; off <<= 1) {
                float ov = __shfl_xor(mo, off, 64);
                int   oj = __shfl_xor(mj, off, 64);
                if (ov > mo || (ov == mo && oj < mj)) { mo = ov; mj = oj; }
            }
            bool valid = (mj != SENT_I);
            if (valid && li[0] == mj) {  // unique winner pops (indices unique per gt)
#pragma unroll
                for (int t = 0; t < 9; ++t) { lv[t] = lv[t + 1]; li[t] = li[t + 1]; }
                lv[9] = -1e30f; li[9] = SENT_I;
            }
            if (lane == q) {
                out[128 + k * 10 + q]        = valid ? mj : -1;
                out[1408 + 128 + k * 10 + q] = valid ? gt : -1;
                if (valid) atomicOr(&bits[mj >> 5], 1u << (mj & 31));
            }
        }
        __syncthreads();  // single wave: cheap; orders bitmap updates vs next scan
    }
}

// ---------- launch ----------

extern "C" void kernel_launch(void* const* d_in, const int* in_sizes, int n_in,
                              void* d_out, int out_size, void* d_ws, size_t ws_size,
                              hipStream_t stream) {
    const float* pc  = (const float*)d_in[0];
    const float* ps  = (const float*)d_in[1];
    const float* cls = (const float*)d_in[2];
    const float* gc  = (const float*)d_in[4];
    const float* gs  = (const float*)d_in[5];
    const int*   lab = (const int*)d_in[6];

    char* ws = (char*)d_ws;
    float*         costT    = (float*)(ws + 0);                      // 33,554,432 B
    double*        v        = (double*)(ws + 33554432);              //    524,288 B (fallback only)
    double*        shortest = (double*)(ws + 34078720);              //    524,288 B (fallback only)
    int*           path     = (int*)(ws + 34603008);                 //    262,144 B (fallback only)
    int*           row4col  = (int*)(ws + 34865152);                 //    262,144 B (fallback only)
    unsigned char* SC       = (unsigned char*)(ws + 35127296);       //     65,536 B (fallback only)
    unsigned*      usedbits = (unsigned*)(ws + 35192832);            //      8,192 B (in old used slot)
    int*           ccnt     = (int*)(ws + 35258368);
    unsigned*      cmax     = (unsigned*)(ws + 35258880);
    int*           order    = (int*)(ws + 35259392);
    int2*          cpair    = (int2*)(ws + 35259904);                // 12,582,912 B
    // sparse-LSA arrays ALIAS fallback-only v/shortest (fallback re-inits them if it runs)
    float*         segval   = (float*)(ws + 33554432);               //    262,144 B (over v)
    int*           segidx   = (int*)(ws + 33554432 + 262144);        //    262,144 B (over v)
    int*           inVmap   = (int*)(ws + 34078720);                 //    262,144 B (over shortest)
    int*           failFlag = (int*)(ws + 34078720 + 262144);        //          4 B (over shortest)

    int* out = (int*)d_out;

    hipLaunchKernelGGL(k_init, dim3(1), dim3(128), 0, stream, ccnt, cmax);
    hipLaunchKernelGGL(k_cost, dim3(NPRED / 256), dim3(256), 0, stream,
                       pc, ps, cls, gc, gs, lab, costT, ccnt, cmax, cpair);
    hipLaunchKernelGGL(k_sort, dim3(1), dim3(128), 0, stream, cmax, order);
    hipLaunchKernelGGL(k_segmin, dim3(16384), dim3(256), 0, stream,
                       costT, segval, segidx, inVmap, failFlag);
    hipLaunchKernelGGL(k_lsa_sparse, dim3(1), dim3(1024), 0, stream,
                       costT, segval, segidx, inVmap, failFlag, usedbits, out);
    hipLaunchKernelGGL(k_lsa_dense, dim3(1), dim3(1024), 0, stream,
                       costT, failFlag, v, shortest, path, row4col, SC, usedbits, out);
    hipLaunchKernelGGL(k_dyn, dim3(1), dim3(64), 0, stream,
                       order, ccnt, cpair, usedbits, out);
}

// Round 6
// 2084.730 us; speedup vs baseline: 1.5904x; 1.5904x over previous
//
#include <hip/hip_runtime.h>
#include <hip/hip_bf16.h>
#include <math.h>

#define NPRED 65536
#define NGT   128
#define NCLS  256
#define CAP   12288
#define VCAP  160
#define KEEP  2048   // sorted-prefix length per gt (power of two for bitonic)
#define KMIN  1418   // >= 128 (LSA) + 10*127 (earlier dyn picks) + 10  -> guarantee
#define SENT_I 0x7FFFFFFF

// ---------- numeric helpers (match reference op order; no FMA contraction) ----------

__device__ __forceinline__ float sigmoid_f32(float x) {
#pragma clang fp contract(off)
    double s = 1.0 / (1.0 + exp(-(double)x));
    return (float)s;
}

// monotone map f32 -> uint32 (order-preserving for all floats)
__device__ __forceinline__ unsigned f2u(float f) {
    unsigned u = __float_as_uint(f);
    return (u & 0x80000000u) ? ~u : (u | 0x80000000u);
}

__device__ __forceinline__ float giou3d(
    float pl0, float pl1, float pl2, float ph0, float ph1, float ph2, float pvol,
    float gl0, float gl1, float gl2, float gh0, float gh1, float gh2, float gvol)
{
#pragma clang fp contract(off)
    float c0 = fmaxf(fminf(ph0, gh0) - fmaxf(pl0, gl0), 0.0f);
    float c1 = fmaxf(fminf(ph1, gh1) - fmaxf(pl1, gl1), 0.0f);
    float c2 = fmaxf(fminf(ph2, gh2) - fmaxf(pl2, gl2), 0.0f);
    float overlap = (c0 * c1) * c2;
    float uni = fmaxf((pvol + gvol) - overlap, 1e-6f);
    float iou = overlap / uni;
    float e0 = fmaxf(fmaxf(ph0, gh0) - fminf(pl0, gl0), 0.0f);
    float e1 = fmaxf(fmaxf(ph1, gh1) - fminf(pl1, gl1), 0.0f);
    float e2 = fmaxf(fmaxf(ph2, gh2) - fminf(pl2, gl2), 0.0f);
    float enc = fmaxf((e0 * e1) * e2, 1e-6f);
    return iou - (enc - uni) / enc;
}

// ---------- kernels ----------

__global__ void k_init(int* ccnt, unsigned* cmax) {
    int t = threadIdx.x;
    if (t < NGT) { ccnt[t] = 0; cmax[t] = 0u; }
}

__global__ __launch_bounds__(256) void k_cost(
    const float* __restrict__ pc, const float* __restrict__ ps,
    const float* __restrict__ cls, const float* __restrict__ gc,
    const float* __restrict__ gs, const int* __restrict__ lab,
    float* __restrict__ costT, int* __restrict__ ccnt, unsigned* __restrict__ cmax,
    int2* __restrict__ cpair)
{
#pragma clang fp contract(off)
    __shared__ float gb[NGT][6];
    __shared__ float gvol[NGT];
    __shared__ int   glab[NGT];
    int tid = threadIdx.x;
    if (tid < NGT) {
        float c0 = gc[tid * 3 + 0], c1 = gc[tid * 3 + 1], c2 = gc[tid * 3 + 2];
        float s0 = gs[tid * 3 + 0], s1 = gs[tid * 3 + 1], s2 = gs[tid * 3 + 2];
        float l0 = c0 - s0 / 2.0f, l1 = c1 - s1 / 2.0f, l2 = c2 - s2 / 2.0f;
        float h0 = c0 + s0 / 2.0f, h1 = c1 + s1 / 2.0f, h2 = c2 + s2 / 2.0f;
        gb[tid][0] = l0; gb[tid][1] = l1; gb[tid][2] = l2;
        gb[tid][3] = h0; gb[tid][4] = h1; gb[tid][5] = h2;
        gvol[tid] = ((h0 - l0) * (h1 - l1)) * (h2 - l2);
        glab[tid] = lab[tid];
    }
    __syncthreads();

    int p = blockIdx.x * 256 + tid;
    float c0 = pc[p * 3 + 0], c1 = pc[p * 3 + 1], c2 = pc[p * 3 + 2];
    float s0 = ps[p * 3 + 0], s1 = ps[p * 3 + 1], s2 = ps[p * 3 + 2];
    float pl0 = c0 - s0 / 2.0f, pl1 = c1 - s1 / 2.0f, pl2 = c2 - s2 / 2.0f;
    float ph0 = c0 + s0 / 2.0f, ph1 = c1 + s1 / 2.0f, ph2 = c2 + s2 / 2.0f;
    float pvol = ((ph0 - pl0) * (ph1 - pl1)) * (ph2 - pl2);
    const float* crow = cls + (size_t)p * NCLS;

    for (int g = 0; g < NGT; ++g) {
        float gio = giou3d(pl0, pl1, pl2, ph0, ph1, ph2, pvol,
                           gb[g][0], gb[g][1], gb[g][2], gb[g][3], gb[g][4], gb[g][5], gvol[g]);
        float m = gio;
        for (int off = 32; off; off >>= 1) m = fmaxf(m, __shfl_xor(m, off, 64));
        if ((tid & 63) == 0) atomicMax(&cmax[g], f2u(m));
        float sg = sigmoid_f32(crow[glab[g]]);
        float tot = (-sg) + (2.0f * (-gio));
        costT[(size_t)g * NPRED + p] = tot;
        if (gio > 0.25f) {
            int slot = atomicAdd(&ccnt[g], 1);
            if (slot < CAP) {
                cpair[(size_t)g * CAP + slot] = make_int2(p, __float_as_int(gio));
            }
        }
    }
}

__global__ __launch_bounds__(128) void k_sort(const unsigned* __restrict__ cmax,
                                              int* __restrict__ order) {
    __shared__ unsigned m[NGT];
    int t = threadIdx.x;
    m[t] = cmax[t];
    __syncthreads();
    unsigned mt = m[t];
    int r = 0;
    for (int k = 0; k < NGT; ++k) {
        unsigned mk = m[k];
        if (mk < mt || (mk == mt && k < t)) r++;
    }
    order[r] = t;
}

// per-(row,segment) min of raw cost, lex (value, index); zero failFlag
// GRID: 128 rows * 512 segs = 65536 waves = 16384 blocks of 4 waves
__global__ __launch_bounds__(256) void k_segmin(
    const float* __restrict__ costT, float* __restrict__ segval, int* __restrict__ segidx,
    int* __restrict__ failFlag)
{
    if (blockIdx.x == 0 && threadIdx.x == 0) *failFlag = 0;
    int wave = blockIdx.x * 4 + (threadIdx.x >> 6);
    int lane = threadIdx.x & 63;
    int row = wave >> 9;
    int seg = wave & 511;
    const float* crow = costT + (size_t)row * NPRED;
    int j0 = seg * 128 + lane;
    float c0 = crow[j0], c1 = crow[j0 + 64];
    float bc; int bj;
    if (c1 < c0) { bc = c1; bj = j0 + 64; } else { bc = c0; bj = j0; }
    for (int off = 1; off < 64; off <<= 1) {
        float oc = __shfl_xor(bc, off, 64);
        int   oj = __shfl_xor(bj, off, 64);
        if (oc < bc || (oc == bc && oj < bj)) { bc = oc; bj = oj; }
    }
    if (lane == 0) { segval[row * 512 + seg] = bc; segidx[row * 512 + seg] = bj; }
}

// per-row min over the 512 segment minima. GRID: 32 blocks x 256 (1 wave per row)
__global__ __launch_bounds__(256) void k_rowmin(
    const float* __restrict__ segval, const int* __restrict__ segidx,
    float* __restrict__ rmv_g, int* __restrict__ rmi_g)
{
    int row = blockIdx.x * 4 + (threadIdx.x >> 6);
    int lane = threadIdx.x & 63;
    float bc = INFINITY; int bj = SENT_I;
    for (int t = 0; t < 8; ++t) {
        int s = t * 64 + lane;
        float c = segval[row * 512 + s];
        int j = segidx[row * 512 + s];
        if (c < bc || (c == bc && j < bj)) { bc = c; bj = j; }
    }
    for (int off = 1; off < 64; off <<= 1) {
        float oc = __shfl_xor(bc, off, 64);
        int oj = __shfl_xor(bj, off, 64);
        if (oc < bc || (oc == bc && oj < bj)) { bc = oc; bj = oj; }
    }
    if (lane == 0) { rmv_g[row] = bc; rmi_g[row] = bj; }
}

// sparse JV LSA, SINGLE WAVE: V = ever-picked columns (<=128) in LDS; fresh
// columns served by cached per-row minima (O(1) heads); repairs fused via the
// lemma rowmin[row]==fixcol => seg-argmin[row, seg(fixcol)]==fixcol.
// Bit-identical to dense numpy JV (exact f64 op order, (v,col,SRpos) lex ties).
__global__ __launch_bounds__(64) void k_lsa_sparse(
    const float* __restrict__ costT,
    float* __restrict__ segval, int* __restrict__ segidx,
    const float* __restrict__ rmv_g, const int* __restrict__ rmi_g,
    int* __restrict__ failFlag,
    unsigned* __restrict__ usedbits, int* __restrict__ out)
{
#pragma clang fp contract(off)
    __shared__ double u_l[NGT];
    __shared__ int    c4r[NGT];
    __shared__ int    slot4row[NGT];
    __shared__ float  rmv[NGT];
    __shared__ int    rmi[NGT];
    __shared__ int    colidV[VCAP];
    __shared__ double vV[VCAP], shortV[VCAP];
    __shared__ int    pathV[VCAP], r4cV[VCAP];
    __shared__ unsigned char SCV[VCAP];
    __shared__ int    SRr[VCAP];
    __shared__ double headv[VCAP];
    __shared__ int    headj[VCAP];
    __shared__ unsigned vbits[2048];
    __shared__ int S_bi, S_sink, S_nSR, S_nV, S_fixcol, S_fail;
    __shared__ double S_mv;

    int lane = threadIdx.x;
    for (int w = lane; w < 2048; w += 64) vbits[w] = 0u;
    for (int r = lane; r < NGT; r += 64) {
        u_l[r] = 0.0; c4r[r] = -1; slot4row[r] = -1;
        rmv[r] = rmv_g[r]; rmi[r] = rmi_g[r];
    }
    if (lane == 0) { S_nV = 0; S_fixcol = -1; S_fail = 0; }
    __syncthreads();

    for (int cur = 0; cur < NGT; ++cur) {
        int fixcol = S_fixcol;
        // repair segment minima + row minima for the column that joined V last round
        if (fixcol >= 0) {
            int seg = fixcol >> 7, base = seg << 7;
            for (int rr = 0; rr < 2; ++rr) {
                int r0 = rr * 64 + lane;
                int sv = segidx[r0 * 512 + seg];
                unsigned long long mm = __ballot(sv == fixcol);
                while (mm) {
                    int mr = __ffsll(mm) - 1;
                    mm &= mm - 1;
                    int row = rr * 64 + mr;
                    float bc = INFINITY; int bj = SENT_I;
                    for (int t = 0; t < 2; ++t) {
                        int j = base + t * 64 + lane;
                        if (!((vbits[j >> 5] >> (j & 31)) & 1u)) {
                            float c = costT[(size_t)row * NPRED + j];
                            if (c < bc || (c == bc && j < bj)) { bc = c; bj = j; }
                        }
                    }
                    for (int off = 1; off < 64; off <<= 1) {
                        float oc = __shfl_xor(bc, off, 64);
                        int   oj = __shfl_xor(bj, off, 64);
                        if (oc < bc || (oc == bc && oj < bj)) { bc = oc; bj = oj; }
                    }
                    if (lane == 0) { segval[row * 512 + seg] = bc; segidx[row * 512 + seg] = bj; }
                    if (rmi[row] == fixcol) {  // rowmin rebuild (lemma: always a phase-A match)
                        float rc = INFINITY; int rj = SENT_I;
                        for (int t = 0; t < 8; ++t) {
                            int s2 = t * 64 + lane;
                            float c; int j2;
                            if (s2 == seg) { c = bc; j2 = bj; }
                            else { c = segval[row * 512 + s2]; j2 = segidx[row * 512 + s2]; }
                            if (c < rc || (c == rc && j2 < rj)) { rc = c; rj = j2; }
                        }
                        for (int off = 1; off < 64; off <<= 1) {
                            float oc = __shfl_xor(rc, off, 64);
                            int   oj = __shfl_xor(rj, off, 64);
                            if (oc < rc || (oc == rc && oj < rj)) { rc = oc; rj = oj; }
                        }
                        if (lane == 0) { rmv[row] = rc; rmi[row] = rj; }
                    }
                }
            }
        }
        __syncthreads();
        // round init
        int nV0 = S_nV;
        for (int k = lane; k < nV0; k += 64) { shortV[k] = INFINITY; pathV[k] = -1; SCV[k] = 0; }
        if (lane == 0) {
            S_bi = cur; S_sink = -1; S_mv = 0.0;
            SRr[0] = cur; S_nSR = 1; S_fixcol = -1;
            int hj = rmi[cur];
            headj[0] = hj;
            headv[0] = (hj == SENT_I) ? (double)INFINITY
                                      : ((0.0 + (double)rmv[cur]) - u_l[cur]);
        }
        __syncthreads();

        while (true) {
            int bi = S_bi; double mv = S_mv; int nV = S_nV; int s = S_nSR;
            double ui = u_l[bi];
            double bv = (double)INFINITY; int bj = SENT_I, bp = SENT_I, baux = -1, bisv = 0;
            // exact scan of V-members for the current row
            for (int k = lane; k < nV; k += 64) {
                if (!SCV[k]) {
                    double c = (double)costT[(size_t)bi * NPRED + colidV[k]];
                    double r = ((mv + c) - ui) - vV[k];
                    if (r < shortV[k]) { shortV[k] = r; pathV[k] = bi; }
                    double sval = shortV[k]; int scol = colidV[k];
                    if (sval < bv || (sval == bv && scol < bj)) {
                        bv = sval; bj = scol; bp = SENT_I; baux = k; bisv = 1;
                    }
                }
            }
            // per-SR-row heads (fresh columns), key (value, column, SR-position)
            for (int p = lane; p < s; p += 64) {
                double hv = headv[p]; int hj = headj[p];
                if (hv < bv || (hv == bv && (hj < bj || (hj == bj && p < bp)))) {
                    bv = hv; bj = hj; bp = p; baux = p; bisv = 0;
                }
            }
            for (int off = 1; off < 64; off <<= 1) {
                double ov = __shfl_xor(bv, off, 64);
                int oj = __shfl_xor(bj, off, 64);
                int op = __shfl_xor(bp, off, 64);
                int oa = __shfl_xor(baux, off, 64);
                int oi = __shfl_xor(bisv, off, 64);
                if (ov < bv || (ov == bv && (oj < bj || (oj == bj && op < bp)))) {
                    bv = ov; bj = oj; bp = op; baux = oa; bisv = oi;
                }
            }
            if (lane == 0) {
                S_mv = bv;
                if (bisv) {
                    SCV[baux] = 1;
                    int nr = r4cV[baux];
                    SRr[s] = nr;
                    int hj = rmi[nr];
                    headj[s] = hj;
                    headv[s] = (hj == SENT_I) ? (double)INFINITY
                                              : ((bv + (double)rmv[nr]) - u_l[nr]);
                    S_nSR = s + 1; S_bi = nr;
                } else {
                    int k2 = S_nV;
                    if (k2 >= VCAP) S_fail = 1;
                    else {
                        colidV[k2] = bj; vV[k2] = 0.0; shortV[k2] = bv;
                        pathV[k2] = SRr[baux]; SCV[k2] = 1; r4cV[k2] = -1;
                        atomicOr(&vbits[bj >> 5], 1u << (bj & 31));
                        S_nV = k2 + 1;
                        S_sink = bj; S_fixcol = bj;
                    }
                }
            }
            __syncthreads();
            if (S_sink >= 0 || S_fail) break;
        }
        if (S_fail) break;

        double mvf = S_mv;
        int nVn = S_nV;
        for (int k = lane; k < nVn; k += 64)
            if (SCV[k]) vV[k] -= (mvf - shortV[k]);
        if (lane == 0) {
            u_l[cur] += mvf;
            int s = S_nSR;
            for (int q = 1; q < s; ++q) {
                int i2 = SRr[q];
                u_l[i2] += mvf - shortV[slot4row[i2]];
            }
            int jslot = S_nV - 1;  // sink's V slot
            while (true) {
                int i2 = pathV[jslot];
                r4cV[jslot] = i2;
                int oldslot = (c4r[i2] >= 0) ? slot4row[i2] : -1;
                c4r[i2] = colidV[jslot];
                slot4row[i2] = jslot;
                if (i2 == cur) break;
                jslot = oldslot;
            }
        }
        __syncthreads();
    }

    if (lane == 0 && S_fail) *failFlag = 1;
    __syncthreads();
    if (!S_fail) {
        for (int w = lane; w < 2048; w += 64) usedbits[w] = 0u;
        __syncthreads();
        for (int r = lane; r < NGT; r += 64) {
            int p = c4r[r];
            atomicOr(&usedbits[p >> 5], 1u << (p & 31));
            out[r] = p;
            out[1408 + r] = r;
        }
    }
}

// dense fallback: only runs if k_lsa_sparse flagged overflow (should never happen)
__global__ __launch_bounds__(1024) void k_lsa_dense(
    const float* __restrict__ costT, const int* __restrict__ failFlag,
    double* __restrict__ v, double* __restrict__ shortest,
    int* __restrict__ path, int* __restrict__ row4col,
    unsigned char* __restrict__ SC, unsigned* __restrict__ usedbits,
    int* __restrict__ out)
{
#pragma clang fp contract(off)
    if (*failFlag == 0) return;
    __shared__ double u_l[NGT];
    __shared__ int    c4r[NGT];
    __shared__ int    SR[NGT + 1];
    __shared__ int    bi, bsink, nSR;
    __shared__ double bmin;
    __shared__ double wval[16];
    __shared__ int    widx[16];
    int tid = threadIdx.x;

    for (int j = tid; j < NPRED; j += 1024) { v[j] = 0.0; row4col[j] = -1; }
    if (tid < NGT) { u_l[tid] = 0.0; c4r[tid] = -1; }
    __syncthreads();

    for (int cur = 0; cur < NGT; ++cur) {
        for (int j = tid; j < NPRED; j += 1024) {
            shortest[j] = (double)INFINITY; path[j] = -1; SC[j] = 0;
        }
        if (tid == 0) { bi = cur; bsink = -1; bmin = 0.0; SR[0] = cur; nSR = 1; }
        __syncthreads();

        while (true) {
            int irow = bi;
            double mv = bmin;
            double ui = u_l[irow];
            const float* crow = costT + (size_t)irow * NPRED;
            double bestv = (double)INFINITY;
            int    bestj = SENT_I;
            for (int j = tid; j < NPRED; j += 1024) {
                if (!SC[j]) {
                    double s = shortest[j];
                    double r = ((mv + (double)crow[j]) - ui) - v[j];
                    if (r < s) { s = r; shortest[j] = r; path[j] = irow; }
                    if (s < bestv || (s == bestv && j < bestj)) { bestv = s; bestj = j; }
                }
            }
            for (int off = 32; off; off >>= 1) {
                double ov = __shfl_down(bestv, off, 64);
                int    oj = __shfl_down(bestj, off, 64);
                if (ov < bestv || (ov == bestv && oj < bestj)) { bestv = ov; bestj = oj; }
            }
            if ((tid & 63) == 0) { wval[tid >> 6] = bestv; widx[tid >> 6] = bestj; }
            __syncthreads();
            if (tid == 0) {
                double bv = wval[0]; int bj = widx[0];
                for (int w = 1; w < 16; ++w) {
                    double ov = wval[w]; int oj = widx[w];
                    if (ov < bv || (ov == bv && oj < bj)) { bv = ov; bj = oj; }
                }
                bmin = bv;
                SC[bj] = 1;
                int r = row4col[bj];
                if (r < 0) { bsink = bj; }
                else       { SR[nSR++] = r; bi = r; }
            }
            __syncthreads();
            if (bsink >= 0) break;
        }

        double mv = bmin;
        for (int j = tid; j < NPRED; j += 1024)
            if (SC[j]) v[j] -= (mv - shortest[j]);
        if (tid == 0) {
            u_l[cur] += mv;
            for (int k = 1; k < nSR; ++k) {
                int i2 = SR[k];
                u_l[i2] += mv - shortest[c4r[i2]];
            }
            int j = bsink;
            while (true) {
                int i2 = path[j];
                row4col[j] = i2;
                int nj = c4r[i2];
                c4r[i2] = j;
                j = nj;
                if (i2 == cur) break;
            }
        }
        __syncthreads();
    }

    for (int w = tid; w < 2048; w += 1024) usedbits[w] = 0u;
    __syncthreads();
    for (int j = tid; j < NPRED; j += 1024)
        if (row4col[j] >= 0) atomicOr(&usedbits[j >> 5], 1u << (j & 31));
    if (tid < NGT) {
        out[tid]        = c4r[tid];
        out[1408 + tid] = tid;
    }
}

// per-gt: histogram-select top >=KMIN by (val desc, idx asc), compact <=KEEP-1,
// bitonic-sort KEEP u64 keys in LDS, write sorted prefix. 128 blocks x 256 thr.
__global__ __launch_bounds__(256) void k_prep(
    const int2* __restrict__ cpair, const int* __restrict__ ccnt,
    unsigned long long* __restrict__ scand, int* __restrict__ kcount,
    int* __restrict__ fullflag)
{
    __shared__ int hist[256];
    __shared__ unsigned long long keys[KEEP];
    __shared__ unsigned sh_pref, sh_thresh;
    __shared__ int sh_done, sh_fail, sh_cnt;
    int tid = threadIdx.x;
    int g = blockIdx.x;
    int nc = ccnt[g]; if (nc > CAP) nc = CAP;
    const int2* src = cpair + (size_t)g * CAP;

    unsigned thresh = 0;
    if (nc > KEEP - 1) {
        if (tid == 0) { sh_pref = 0; sh_done = 0; sh_fail = 0; }
        __syncthreads();
        int above = 0;  // live only on tid 0
        for (int byt = 3; byt >= 0; --byt) {
            hist[tid] = 0;
            __syncthreads();
            unsigned pref = sh_pref;
            for (int c = tid; c < nc; c += 256) {
                unsigned u = f2u(__int_as_float(src[c].y));
                if (byt == 3 || (u >> ((byt + 1) * 8)) == (pref >> ((byt + 1) * 8)))
                    atomicAdd(&hist[(u >> (byt * 8)) & 255], 1);
            }
            __syncthreads();
            if (tid == 0) {
                int cum = 0, B = 0, kept = 0, abnew = above;
                for (int b = 255; b >= 0; --b) {
                    if (above + cum + hist[b] >= KMIN) {
                        B = b; kept = above + cum + hist[b]; abnew = above + cum; break;
                    }
                    cum += hist[b];
                }
                if (kept <= KEEP - 1) { sh_thresh = sh_pref | ((unsigned)B << (byt * 8)); sh_done = 1; }
                else {
                    above = abnew;
                    sh_pref = sh_pref | ((unsigned)B << (byt * 8));
                    if (byt == 0) sh_fail = 1;
                }
            }
            __syncthreads();
            if (sh_done || sh_fail) break;
        }
        if (sh_fail) {
            if (tid == 0) { fullflag[g] = 1; kcount[g] = 0; }
            return;
        }
        thresh = sh_thresh;
    }
    if (tid == 0) sh_cnt = 0;
    __syncthreads();
    for (int c = tid; c < nc; c += 256) {
        unsigned u = f2u(__int_as_float(src[c].y));
        if (u >= thresh) {
            int slot = atomicAdd(&sh_cnt, 1);
            keys[slot] = ((unsigned long long)(~u) << 32) | (unsigned)src[c].x;
        }
    }
    __syncthreads();
    int kept = sh_cnt;
    for (int i = tid; i < KEEP; i += 256) if (i >= kept) keys[i] = ~0ull;
    __syncthreads();
    for (int k = 2; k <= KEEP; k <<= 1) {
        for (int j = k >> 1; j > 0; j >>= 1) {
            for (int i = tid; i < KEEP; i += 256) {
                int ixj = i ^ j;
                if (ixj > i) {
                    unsigned long long a = keys[i], b = keys[ixj];
                    bool up = ((i & k) == 0);
                    if ((up && a > b) || (!up && a < b)) { keys[i] = b; keys[ixj] = a; }
                }
            }
            __syncthreads();
        }
    }
    for (int i = tid; i < KEEP; i += 256) scand[(size_t)g * KEEP + i] = keys[i];
    if (tid == 0) { kcount[g] = kept; fullflag[g] = 0; }
}

// sequential dynamic assignment, SINGLE WAVE: walk each gt's sorted prefix,
// ballot/popcount rank-select first 10 unused; LDS used-bitmap.
__global__ __launch_bounds__(64) void k_dyn2(
    const int* __restrict__ order, const int* __restrict__ kcount,
    const unsigned long long* __restrict__ scand, const int* __restrict__ fullflag,
    const int* __restrict__ ccnt, const int2* __restrict__ cpair,
    const unsigned* __restrict__ usedbits_g, const int* __restrict__ failFlag,
    int* __restrict__ out)
{
    __shared__ unsigned bits[2048];
    int lane = threadIdx.x;
    for (int w = lane; w < 2048; w += 64) bits[w] = usedbits_g[w];
    __syncthreads();
    bool globalFull = (*failFlag != 0);

    for (int k = 0; k < NGT; ++k) {
        int gt = order[k];
        int got = 0;
        if (!globalFull && fullflag[gt] == 0) {
            int kept = kcount[gt];
            int base = 0;
            while (got < 10 && base < kept) {
                int i = base + lane;
                unsigned long long key = (i < kept) ? scand[(size_t)gt * KEEP + i] : ~0ull;
                int p = (int)(unsigned)(key & 0xFFFFFFFFull);
                bool ok = (key != ~0ull) && !((bits[p >> 5] >> (p & 31)) & 1u);
                unsigned long long mask = __ballot(ok);
                int need = 10 - got;
                int pre = __popcll(mask & ((1ull << lane) - 1ull));
                if (ok && pre < need) {
                    out[128 + k * 10 + got + pre] = p;
                    out[1408 + 128 + k * 10 + got + pre] = gt;
                    atomicOr(&bits[p >> 5], 1u << (p & 31));
                }
                int tot = __popcll(mask);
                got += (tot < need) ? tot : need;
                base += 64;
                __syncthreads();
            }
        } else {
            // fallback: full candidate scan (never taken in practice)
            int nc = ccnt[gt]; if (nc > CAP) nc = CAP;
            float lv[10]; int li[10];
#pragma unroll
            for (int q = 0; q < 10; ++q) { lv[q] = -1e30f; li[q] = SENT_I; }
            for (int c = lane; c < nc; c += 64) {
                int2 pr = cpair[(size_t)gt * CAP + c];
                int p = pr.x;
                if ((bits[p >> 5] >> (p & 31)) & 1u) continue;
                float cv = __int_as_float(pr.y); int ci = p;
#pragma unroll
                for (int q = 0; q < 10; ++q) {
                    bool b = (cv > lv[q]) || (cv == lv[q] && ci < li[q]);
                    float tv = b ? lv[q] : cv; int ti = b ? li[q] : ci;
                    if (b) { lv[q] = cv; li[q] = ci; }
                    cv = tv; ci = ti;
                }
            }
#pragma unroll
            for (int q = 0; q < 10; ++q) {
                float mo = lv[0]; int mj = li[0];
#pragma unroll
                for (int off = 1; off < 64; off <<= 1) {
                    float ov = __shfl_xor(mo, off, 64);
                    int oj = __shfl_xor(mj, off, 64);
                    if (ov > mo || (ov == mo && oj < mj)) { mo = ov; mj = oj; }
                }
                bool valid = (mj != SENT_I);
                if (valid && li[0] == mj) {
#pragma unroll
                    for (int t = 0; t < 9; ++t) { lv[t] = lv[t + 1]; li[t] = li[t + 1]; }
                    lv[9] = -1e30f; li[9] = SENT_I;
                }
                if (lane == q) {
                    out[128 + k * 10 + q] = valid ? mj : -1;
                    out[1408 + 128 + k * 10 + q] = valid ? gt : -1;
                    if (valid) atomicOr(&bits[mj >> 5], 1u << (mj & 31));
                }
            }
            got = 10;
            __syncthreads();
        }
        for (int q = got + lane; q < 10; q += 64) {
            out[128 + k * 10 + q] = -1;
            out[1408 + 128 + k * 10 + q] = -1;
        }
        __syncthreads();
    }
}

// ---------- launch ----------

extern "C" void kernel_launch(void* const* d_in, const int* in_sizes, int n_in,
                              void* d_out, int out_size, void* d_ws, size_t ws_size,
                              hipStream_t stream) {
    const float* pc  = (const float*)d_in[0];
    const float* ps  = (const float*)d_in[1];
    const float* cls = (const float*)d_in[2];
    const float* gc  = (const float*)d_in[4];
    const float* gs  = (const float*)d_in[5];
    const int*   lab = (const int*)d_in[6];

    char* ws = (char*)d_ws;
    float*         costT    = (float*)(ws + 0);                  // 33,554,432
    // scand ALIASES costT[0..2MB]: k_prep launched after k_lsa_sparse/k_lsa_dense
    unsigned long long* scand = (unsigned long long*)(ws + 0);   //  2,097,152 (over costT)
    float*         segval   = (float*)(ws + 33554432);           //    262,144
    int*           segidx   = (int*)(ws + 33816576);             //    262,144
    // dense-fallback scratch: v aliases segval+segidx (dead if fallback runs)
    double*        v        = (double*)(ws + 33554432);          //    524,288 (over segval/segidx)
    double*        shortest = (double*)(ws + 34078720);          //    524,288
    int*           path     = (int*)(ws + 34603008);             //    262,144
    int*           row4col  = (int*)(ws + 34865152);             //    262,144
    unsigned char* SC       = (unsigned char*)(ws + 35127296);   //     65,536
    int*           kcount   = (int*)(ws + 35192832);             //        512
    int*           fullflag = (int*)(ws + 35193344);             //        512
    int*           ccnt     = (int*)(ws + 35193856);             //        512
    unsigned*      cmax     = (unsigned*)(ws + 35194368);        //        512
    int*           order    = (int*)(ws + 35194880);             //        512
    float*         rmv_g    = (float*)(ws + 35195392);           //        512
    int*           rmi_g    = (int*)(ws + 35195904);             //        512
    int*           failFlag = (int*)(ws + 35196416);             //        512
    unsigned*      usedbits = (unsigned*)(ws + 35196928);        //      8,192
    int2*          cpair    = (int2*)(ws + 35205120);            // 12,582,912 -> end 47,788,032

    int* out = (int*)d_out;

    hipLaunchKernelGGL(k_init, dim3(1), dim3(128), 0, stream, ccnt, cmax);
    hipLaunchKernelGGL(k_cost, dim3(NPRED / 256), dim3(256), 0, stream,
                       pc, ps, cls, gc, gs, lab, costT, ccnt, cmax, cpair);
    hipLaunchKernelGGL(k_sort, dim3(1), dim3(128), 0, stream, cmax, order);
    hipLaunchKernelGGL(k_segmin, dim3(16384), dim3(256), 0, stream,
                       costT, segval, segidx, failFlag);
    hipLaunchKernelGGL(k_rowmin, dim3(32), dim3(256), 0, stream,
                       segval, segidx, rmv_g, rmi_g);
    hipLaunchKernelGGL(k_lsa_sparse, dim3(1), dim3(64), 0, stream,
                       costT, segval, segidx, rmv_g, rmi_g, failFlag, usedbits, out);
    hipLaunchKernelGGL(k_lsa_dense, dim3(1), dim3(1024), 0, stream,
                       costT, failFlag, v, shortest, path, row4col, SC, usedbits, out);
    hipLaunchKernelGGL(k_prep, dim3(NGT), dim3(256), 0, stream,
                       cpair, ccnt, scand, kcount, fullflag);
    hipLaunchKernelGGL(k_dyn2, dim3(1), dim3(64), 0, stream,
                       order, kcount, scand, fullflag, ccnt, cpair, usedbits, failFlag, out);
}

// Round 7
// 1787.632 us; speedup vs baseline: 1.8547x; 1.1662x over previous
//
#include <hip/hip_runtime.h>
#include <hip/hip_bf16.h>
#include <math.h>

#define NPRED 65536
#define NGT   128
#define NCLS  256
#define CAP   12288
#define VCAP  160
#define NLIST 129    // per-row sorted prefix: 128 (max |V|) + 1 guarantees a fresh head
#define LSTRIDE 132
#define KEEP  2048
#define KMIN  1418
#define SENT_I 0x7FFFFFFF

// ---------- numeric helpers (match reference op order; no FMA contraction) ----------

__device__ __forceinline__ float sigmoid_f32(float x) {
#pragma clang fp contract(off)
    double s = 1.0 / (1.0 + exp(-(double)x));
    return (float)s;
}

// monotone map f32 -> uint32 (order-preserving for all floats)
__device__ __forceinline__ unsigned f2u(float f) {
    unsigned u = __float_as_uint(f);
    return (u & 0x80000000u) ? ~u : (u | 0x80000000u);
}
__device__ __forceinline__ float u2f(unsigned x) {
    unsigned u = (x & 0x80000000u) ? (x ^ 0x80000000u) : ~x;
    return __uint_as_float(u);
}

__device__ __forceinline__ float giou3d(
    float pl0, float pl1, float pl2, float ph0, float ph1, float ph2, float pvol,
    float gl0, float gl1, float gl2, float gh0, float gh1, float gh2, float gvol)
{
#pragma clang fp contract(off)
    float c0 = fmaxf(fminf(ph0, gh0) - fmaxf(pl0, gl0), 0.0f);
    float c1 = fmaxf(fminf(ph1, gh1) - fmaxf(pl1, gl1), 0.0f);
    float c2 = fmaxf(fminf(ph2, gh2) - fmaxf(pl2, gl2), 0.0f);
    float overlap = (c0 * c1) * c2;
    float uni = fmaxf((pvol + gvol) - overlap, 1e-6f);
    float iou = overlap / uni;
    float e0 = fmaxf(fmaxf(ph0, gh0) - fminf(pl0, gl0), 0.0f);
    float e1 = fmaxf(fmaxf(ph1, gh1) - fminf(pl1, gl1), 0.0f);
    float e2 = fmaxf(fmaxf(ph2, gh2) - fminf(pl2, gl2), 0.0f);
    float enc = fmaxf((e0 * e1) * e2, 1e-6f);
    return iou - (enc - uni) / enc;
}

// ---------- kernels ----------

__global__ void k_init(int* ccnt, unsigned* cmax, int* failFlag) {
    int t = threadIdx.x;
    if (t < NGT) { ccnt[t] = 0; cmax[t] = 0u; }
    if (t == 0) *failFlag = 0;
}

__global__ __launch_bounds__(256) void k_cost(
    const float* __restrict__ pc, const float* __restrict__ ps,
    const float* __restrict__ cls, const float* __restrict__ gc,
    const float* __restrict__ gs, const int* __restrict__ lab,
    float* __restrict__ costT, int* __restrict__ ccnt, unsigned* __restrict__ cmax,
    int2* __restrict__ cpair)
{
#pragma clang fp contract(off)
    __shared__ float gb[NGT][6];
    __shared__ float gvol[NGT];
    __shared__ int   glab[NGT];
    int tid = threadIdx.x;
    int lane = tid & 63;
    if (tid < NGT) {
        float c0 = gc[tid * 3 + 0], c1 = gc[tid * 3 + 1], c2 = gc[tid * 3 + 2];
        float s0 = gs[tid * 3 + 0], s1 = gs[tid * 3 + 1], s2 = gs[tid * 3 + 2];
        float l0 = c0 - s0 / 2.0f, l1 = c1 - s1 / 2.0f, l2 = c2 - s2 / 2.0f;
        float h0 = c0 + s0 / 2.0f, h1 = c1 + s1 / 2.0f, h2 = c2 + s2 / 2.0f;
        gb[tid][0] = l0; gb[tid][1] = l1; gb[tid][2] = l2;
        gb[tid][3] = h0; gb[tid][4] = h1; gb[tid][5] = h2;
        gvol[tid] = ((h0 - l0) * (h1 - l1)) * (h2 - l2);
        glab[tid] = lab[tid];
    }
    __syncthreads();

    int p = blockIdx.x * 256 + tid;
    float c0 = pc[p * 3 + 0], c1 = pc[p * 3 + 1], c2 = pc[p * 3 + 2];
    float s0 = ps[p * 3 + 0], s1 = ps[p * 3 + 1], s2 = ps[p * 3 + 2];
    float pl0 = c0 - s0 / 2.0f, pl1 = c1 - s1 / 2.0f, pl2 = c2 - s2 / 2.0f;
    float ph0 = c0 + s0 / 2.0f, ph1 = c1 + s1 / 2.0f, ph2 = c2 + s2 / 2.0f;
    float pvol = ((ph0 - pl0) * (ph1 - pl1)) * (ph2 - pl2);
    const float* crow = cls + (size_t)p * NCLS;

    for (int g = 0; g < NGT; ++g) {
        float gio = giou3d(pl0, pl1, pl2, ph0, ph1, ph2, pvol,
                           gb[g][0], gb[g][1], gb[g][2], gb[g][3], gb[g][4], gb[g][5], gvol[g]);
        float m = gio;
        for (int off = 32; off; off >>= 1) m = fmaxf(m, __shfl_xor(m, off, 64));
        if (lane == 0) atomicMax(&cmax[g], f2u(m));
        float sg = sigmoid_f32(crow[glab[g]]);
        float tot = (-sg) + (2.0f * (-gio));
        costT[(size_t)g * NPRED + p] = tot;
        // wave-aggregated candidate append: 1 atomic per wave per gt
        bool cand = (gio > 0.25f);
        unsigned long long mask = __ballot(cand);
        int cnt = __popcll(mask);
        int base = 0;
        if (lane == 0 && cnt) base = atomicAdd(&ccnt[g], cnt);
        base = __shfl(base, 0, 64);
        if (cand) {
            int slot = base + __popcll(mask & ((1ull << lane) - 1ull));
            if (slot < CAP) cpair[(size_t)g * CAP + slot] = make_int2(p, __float_as_int(gio));
        }
    }
}

__global__ __launch_bounds__(128) void k_sort(const unsigned* __restrict__ cmax,
                                              int* __restrict__ order) {
    __shared__ unsigned m[NGT];
    int t = threadIdx.x;
    m[t] = cmax[t];
    __syncthreads();
    unsigned mt = m[t];
    int r = 0;
    for (int k = 0; k < NGT; ++k) {
        unsigned mk = m[k];
        if (mk < mt || (mk == mt && k < t)) r++;
    }
    order[r] = t;
}

// per-row exact top-NLIST smallest (value, col) via 8-pass u64 radix-select
// (keys are unique: low 32 bits = col). 128 blocks x 256 threads.
__global__ __launch_bounds__(256) void k_toprow(
    const float* __restrict__ costT, int2* __restrict__ rowlist)
{
    __shared__ int hist[256];
    __shared__ unsigned long long keys[256];
    __shared__ unsigned long long sh_prefix;
    __shared__ int sh_rank, sh_cnt;
    int tid = threadIdx.x;
    int row = blockIdx.x;
    const float* crow = costT + (size_t)row * NPRED;
    if (tid == 0) { sh_prefix = 0ull; sh_rank = NLIST - 1; sh_cnt = 0; }
    __syncthreads();
    for (int d = 7; d >= 0; --d) {
        hist[tid] = 0;
        __syncthreads();
        unsigned long long pref = sh_prefix;
        int sh = (d + 1) * 8;
        for (int j = tid; j < NPRED; j += 256) {
            unsigned long long key = ((unsigned long long)f2u(crow[j]) << 32) | (unsigned)j;
            bool match = (sh >= 64) || ((key >> sh) == (pref >> sh));
            if (match) atomicAdd(&hist[(int)((key >> (d * 8)) & 255ull)], 1);
        }
        __syncthreads();
        if (tid == 0) {
            int rank = sh_rank, cum = 0, b = 0;
            for (; b < 256; ++b) { if (cum + hist[b] > rank) break; cum += hist[b]; }
            sh_prefix = pref | ((unsigned long long)b << (d * 8));
            sh_rank = rank - cum;
        }
        __syncthreads();
    }
    unsigned long long thr = sh_prefix;  // exact NLIST-th smallest key
    for (int j = tid; j < NPRED; j += 256) {
        unsigned long long key = ((unsigned long long)f2u(crow[j]) << 32) | (unsigned)j;
        if (key <= thr) { int s = atomicAdd(&sh_cnt, 1); keys[s] = key; }
    }
    __syncthreads();
    if (tid >= sh_cnt) keys[tid] = ~0ull;
    __syncthreads();
    for (int k = 2; k <= 256; k <<= 1) {
        for (int j2 = k >> 1; j2 > 0; j2 >>= 1) {
            int i = tid, ixj = i ^ j2;
            if (ixj > i) {
                unsigned long long a = keys[i], b2 = keys[ixj];
                bool up = ((i & k) == 0);
                if ((up && a > b2) || (!up && a < b2)) { keys[i] = b2; keys[ixj] = a; }
            }
            __syncthreads();
        }
    }
    if (tid < NLIST) {
        unsigned long long key = keys[tid];
        rowlist[row * LSTRIDE + tid] =
            make_int2(__float_as_int(u2f((unsigned)(key >> 32))),
                      (int)(unsigned)(key & 0xFFFFFFFFull));
    }
}

// sparse JV LSA, single wave. Fresh-column heads come from per-row sorted
// top-NLIST lists (first entry not in V == exact argmin over fresh columns).
// Bit-identical to dense numpy JV (exact f64 op order, (v,col,SRpos) lex ties).
__global__ __launch_bounds__(64) void k_lsa_sparse(
    const float* __restrict__ costT, const int2* __restrict__ rowlist,
    int* __restrict__ failFlag,
    unsigned* __restrict__ usedbits, int* __restrict__ out)
{
#pragma clang fp contract(off)
    __shared__ double u_l[NGT];
    __shared__ int    c4r[NGT];
    __shared__ int    slot4row[NGT];
    __shared__ int    headpos[NGT];
    __shared__ int    colidV[VCAP];
    __shared__ double vV[VCAP], shortV[VCAP];
    __shared__ int    pathV[VCAP], r4cV[VCAP];
    __shared__ unsigned char SCV[VCAP];
    __shared__ int    SRr[VCAP];
    __shared__ double headv[VCAP];
    __shared__ int    headj[VCAP];
    __shared__ unsigned vbits[2048];
    __shared__ int S_bi, S_sink, S_nSR, S_nV, S_fail, S_pendrow, S_pendpos;
    __shared__ double S_mv, S_pendmv;

    int lane = threadIdx.x;
    for (int w = lane; w < 2048; w += 64) vbits[w] = 0u;
    for (int r = lane; r < NGT; r += 64) {
        u_l[r] = 0.0; c4r[r] = -1; slot4row[r] = -1; headpos[r] = 0;
    }
    if (lane == 0) { S_nV = 0; S_fail = 0; }
    __syncthreads();

    for (int cur = 0; cur < NGT; ++cur) {
        int nV0 = S_nV;
        for (int k = lane; k < nV0; k += 64) { shortV[k] = INFINITY; pathV[k] = -1; SCV[k] = 0; }
        if (lane == 0) {
            S_bi = cur; S_sink = -1; S_mv = 0.0;
            SRr[0] = cur; S_nSR = 1;
            S_pendrow = cur; S_pendpos = 0; S_pendmv = 0.0;
        }
        __syncthreads();

        while (true) {
            // resolve pending head (whole-wave list walk, coalesced 512B loads)
            int prow = S_pendrow;
            if (prow >= 0) {
                int pos = headpos[prow];
                float hval = 0.0f; int hcol = SENT_I;
                while (pos < NLIST) {
                    int i = pos + lane;
                    int2 e = (i < NLIST) ? rowlist[prow * LSTRIDE + i] : make_int2(0, SENT_I);
                    int c = e.y;
                    bool fresh = (i < NLIST) && !((vbits[c >> 5] >> (c & 31)) & 1u);
                    unsigned long long m = __ballot(fresh);
                    if (m) {
                        int fl = __ffsll(m) - 1;
                        hcol = __shfl(c, fl, 64);
                        hval = __shfl(__int_as_float(e.x), fl, 64);
                        pos += fl;
                        break;
                    }
                    pos += 64;
                }
                if (lane == 0) {
                    headpos[prow] = pos;  // entries before pos are in V forever
                    int pp = S_pendpos;
                    headj[pp] = hcol;
                    headv[pp] = (hcol == SENT_I) ? (double)INFINITY
                                                 : ((S_pendmv + (double)hval) - u_l[prow]);
                    S_pendrow = -1;
                }
                __syncthreads();
            }

            int bi = S_bi; double mv = S_mv; int nV = S_nV; int s = S_nSR;
            double ui = u_l[bi];
            double bv = (double)INFINITY; int bj = SENT_I, bp = SENT_I, baux = -1, bisv = 0;
            // exact scan of V-members for the current row
            for (int k = lane; k < nV; k += 64) {
                if (!SCV[k]) {
                    double c = (double)costT[(size_t)bi * NPRED + colidV[k]];
                    double r = ((mv + c) - ui) - vV[k];
                    if (r < shortV[k]) { shortV[k] = r; pathV[k] = bi; }
                    double sval = shortV[k]; int scol = colidV[k];
                    if (sval < bv || (sval == bv && scol < bj)) {
                        bv = sval; bj = scol; bp = SENT_I; baux = k; bisv = 1;
                    }
                }
            }
            // per-SR-row heads (fresh columns), key (value, column, SR-position)
            for (int p = lane; p < s; p += 64) {
                double hv = headv[p]; int hj = headj[p];
                if (hv < bv || (hv == bv && (hj < bj || (hj == bj && p < bp)))) {
                    bv = hv; bj = hj; bp = p; baux = p; bisv = 0;
                }
            }
            for (int off = 1; off < 64; off <<= 1) {
                double ov = __shfl_xor(bv, off, 64);
                int oj = __shfl_xor(bj, off, 64);
                int op = __shfl_xor(bp, off, 64);
                int oa = __shfl_xor(baux, off, 64);
                int oi = __shfl_xor(bisv, off, 64);
                if (ov < bv || (ov == bv && (oj < bj || (oj == bj && op < bp)))) {
                    bv = ov; bj = oj; bp = op; baux = oa; bisv = oi;
                }
            }
            if (lane == 0) {
                S_mv = bv;
                if (bisv) {
                    SCV[baux] = 1;
                    int nr = r4cV[baux];
                    SRr[s] = nr;
                    headv[s] = (double)INFINITY; headj[s] = SENT_I;  // filled next iter
                    S_pendrow = nr; S_pendpos = s; S_pendmv = bv;
                    S_nSR = s + 1; S_bi = nr;
                } else {
                    int k2 = S_nV;
                    if (k2 >= VCAP) S_fail = 1;
                    else {
                        colidV[k2] = bj; vV[k2] = 0.0; shortV[k2] = bv;
                        pathV[k2] = SRr[baux]; SCV[k2] = 1; r4cV[k2] = -1;
                        vbits[bj >> 5] |= (1u << (bj & 31));
                        S_nV = k2 + 1;
                        S_sink = bj;
                    }
                }
            }
            __syncthreads();
            if (S_sink >= 0 || S_fail) break;
        }
        if (S_fail) break;

        double mvf = S_mv;
        int nVn = S_nV;
        for (int k = lane; k < nVn; k += 64)
            if (SCV[k]) vV[k] -= (mvf - shortV[k]);
        if (lane == 0) {
            u_l[cur] += mvf;
            int s = S_nSR;
            for (int q = 1; q < s; ++q) {
                int i2 = SRr[q];
                u_l[i2] += mvf - shortV[slot4row[i2]];
            }
            int jslot = S_nV - 1;  // sink's V slot
            while (true) {
                int i2 = pathV[jslot];
                r4cV[jslot] = i2;
                int oldslot = (c4r[i2] >= 0) ? slot4row[i2] : -1;
                c4r[i2] = colidV[jslot];
                slot4row[i2] = jslot;
                if (i2 == cur) break;
                jslot = oldslot;
            }
        }
        __syncthreads();
    }

    if (lane == 0 && S_fail) *failFlag = 1;
    __syncthreads();
    if (!S_fail) {
        for (int w = lane; w < 2048; w += 64) usedbits[w] = 0u;
        __syncthreads();
        for (int r = lane; r < NGT; r += 64) {
            int p = c4r[r];
            atomicOr(&usedbits[p >> 5], 1u << (p & 31));
            out[r] = p;
            out[1408 + r] = r;
        }
    }
}

// dense fallback: only runs if k_lsa_sparse flagged overflow (should never happen)
__global__ __launch_bounds__(1024) void k_lsa_dense(
    const float* __restrict__ costT, const int* __restrict__ failFlag,
    double* __restrict__ v, double* __restrict__ shortest,
    int* __restrict__ path, int* __restrict__ row4col,
    unsigned char* __restrict__ SC, unsigned* __restrict__ usedbits,
    int* __restrict__ out)
{
#pragma clang fp contract(off)
    if (*failFlag == 0) return;
    __shared__ double u_l[NGT];
    __shared__ int    c4r[NGT];
    __shared__ int    SR[NGT + 1];
    __shared__ int    bi, bsink, nSR;
    __shared__ double bmin;
    __shared__ double wval[16];
    __shared__ int    widx[16];
    int tid = threadIdx.x;

    for (int j = tid; j < NPRED; j += 1024) { v[j] = 0.0; row4col[j] = -1; }
    if (tid < NGT) { u_l[tid] = 0.0; c4r[tid] = -1; }
    __syncthreads();

    for (int cur = 0; cur < NGT; ++cur) {
        for (int j = tid; j < NPRED; j += 1024) {
            shortest[j] = (double)INFINITY; path[j] = -1; SC[j] = 0;
        }
        if (tid == 0) { bi = cur; bsink = -1; bmin = 0.0; SR[0] = cur; nSR = 1; }
        __syncthreads();

        while (true) {
            int irow = bi;
            double mv = bmin;
            double ui = u_l[irow];
            const float* crow = costT + (size_t)irow * NPRED;
            double bestv = (double)INFINITY;
            int    bestj = SENT_I;
            for (int j = tid; j < NPRED; j += 1024) {
                if (!SC[j]) {
                    double s = shortest[j];
                    double r = ((mv + (double)crow[j]) - ui) - v[j];
                    if (r < s) { s = r; shortest[j] = r; path[j] = irow; }
                    if (s < bestv || (s == bestv && j < bestj)) { bestv = s; bestj = j; }
                }
            }
            for (int off = 32; off; off >>= 1) {
                double ov = __shfl_down(bestv, off, 64);
                int    oj = __shfl_down(bestj, off, 64);
                if (ov < bestv || (ov == bestv && oj < bestj)) { bestv = ov; bestj = oj; }
            }
            if ((tid & 63) == 0) { wval[tid >> 6] = bestv; widx[tid >> 6] = bestj; }
            __syncthreads();
            if (tid == 0) {
                double bv = wval[0]; int bj = widx[0];
                for (int w = 1; w < 16; ++w) {
                    double ov = wval[w]; int oj = widx[w];
                    if (ov < bv || (ov == bv && oj < bj)) { bv = ov; bj = oj; }
                }
                bmin = bv;
                SC[bj] = 1;
                int r = row4col[bj];
                if (r < 0) { bsink = bj; }
                else       { SR[nSR++] = r; bi = r; }
            }
            __syncthreads();
            if (bsink >= 0) break;
        }

        double mv = bmin;
        for (int j = tid; j < NPRED; j += 1024)
            if (SC[j]) v[j] -= (mv - shortest[j]);
        if (tid == 0) {
            u_l[cur] += mv;
            for (int k = 1; k < nSR; ++k) {
                int i2 = SR[k];
                u_l[i2] += mv - shortest[c4r[i2]];
            }
            int j = bsink;
            while (true) {
                int i2 = path[j];
                row4col[j] = i2;
                int nj = c4r[i2];
                c4r[i2] = j;
                j = nj;
                if (i2 == cur) break;
            }
        }
        __syncthreads();
    }

    for (int w = tid; w < 2048; w += 1024) usedbits[w] = 0u;
    __syncthreads();
    for (int j = tid; j < NPRED; j += 1024)
        if (row4col[j] >= 0) atomicOr(&usedbits[j >> 5], 1u << (j & 31));
    if (tid < NGT) {
        out[tid]        = c4r[tid];
        out[1408 + tid] = tid;
    }
}

// per-gt: histogram-select top >=KMIN by (val desc, idx asc), compact <=KEEP-1,
// bitonic-sort KEEP u64 keys in LDS, write sorted prefix. 128 blocks x 256 thr.
__global__ __launch_bounds__(256) void k_prep(
    const int2* __restrict__ cpair, const int* __restrict__ ccnt,
    unsigned long long* __restrict__ scand, int* __restrict__ kcount,
    int* __restrict__ fullflag)
{
    __shared__ int hist[256];
    __shared__ unsigned long long keys[KEEP];
    __shared__ unsigned sh_pref, sh_thresh;
    __shared__ int sh_done, sh_fail, sh_cnt;
    int tid = threadIdx.x;
    int g = blockIdx.x;
    int nc = ccnt[g]; if (nc > CAP) nc = CAP;
    const int2* src = cpair + (size_t)g * CAP;

    unsigned thresh = 0;
    if (nc > KEEP - 1) {
        if (tid == 0) { sh_pref = 0; sh_done = 0; sh_fail = 0; }
        __syncthreads();
        int above = 0;  // live only on tid 0
        for (int byt = 3; byt >= 0; --byt) {
            hist[tid] = 0;
            __syncthreads();
            unsigned pref = sh_pref;
            for (int c = tid; c < nc; c += 256) {
                unsigned u = f2u(__int_as_float(src[c].y));
                if (byt == 3 || (u >> ((byt + 1) * 8)) == (pref >> ((byt + 1) * 8)))
                    atomicAdd(&hist[(u >> (byt * 8)) & 255], 1);
            }
            __syncthreads();
            if (tid == 0) {
                int cum = 0, B = 0, kept = 0, abnew = above;
                for (int b = 255; b >= 0; --b) {
                    if (above + cum + hist[b] >= KMIN) {
                        B = b; kept = above + cum + hist[b]; abnew = above + cum; break;
                    }
                    cum += hist[b];
                }
                if (kept <= KEEP - 1) { sh_thresh = sh_pref | ((unsigned)B << (byt * 8)); sh_done = 1; }
                else {
                    above = abnew;
                    sh_pref = sh_pref | ((unsigned)B << (byt * 8));
                    if (byt == 0) sh_fail = 1;
                }
            }
            __syncthreads();
            if (sh_done || sh_fail) break;
        }
        if (sh_fail) {
            if (tid == 0) { fullflag[g] = 1; kcount[g] = 0; }
            return;
        }
        thresh = sh_thresh;
    }
    if (tid == 0) sh_cnt = 0;
    __syncthreads();
    for (int c = tid; c < nc; c += 256) {
        unsigned u = f2u(__int_as_float(src[c].y));
        if (u >= thresh) {
            int slot = atomicAdd(&sh_cnt, 1);
            keys[slot] = ((unsigned long long)(~u) << 32) | (unsigned)src[c].x;
        }
    }
    __syncthreads();
    int kept = sh_cnt;
    for (int i = tid; i < KEEP; i += 256) if (i >= kept) keys[i] = ~0ull;
    __syncthreads();
    for (int k = 2; k <= KEEP; k <<= 1) {
        for (int j = k >> 1; j > 0; j >>= 1) {
            for (int i = tid; i < KEEP; i += 256) {
                int ixj = i ^ j;
                if (ixj > i) {
                    unsigned long long a = keys[i], b = keys[ixj];
                    bool up = ((i & k) == 0);
                    if ((up && a > b) || (!up && a < b)) { keys[i] = b; keys[ixj] = a; }
                }
            }
            __syncthreads();
        }
    }
    for (int i = tid; i < KEEP; i += 256) scand[(size_t)g * KEEP + i] = keys[i];
    if (tid == 0) { kcount[g] = kept; fullflag[g] = 0; }
}

// sequential dynamic assignment, single wave: walk each gt's sorted prefix,
// ballot/popcount rank-select first 10 unused; LDS used-bitmap.
__global__ __launch_bounds__(64) void k_dyn2(
    const int* __restrict__ order, const int* __restrict__ kcount,
    const unsigned long long* __restrict__ scand, const int* __restrict__ fullflag,
    const int* __restrict__ ccnt, const int2* __restrict__ cpair,
    const unsigned* __restrict__ usedbits_g, const int* __restrict__ failFlag,
    int* __restrict__ out)
{
    __shared__ unsigned bits[2048];
    int lane = threadIdx.x;
    for (int w = lane; w < 2048; w += 64) bits[w] = usedbits_g[w];
    __syncthreads();
    bool globalFull = (*failFlag != 0);

    for (int k = 0; k < NGT; ++k) {
        int gt = order[k];
        int got = 0;
        if (!globalFull && fullflag[gt] == 0) {
            int kept = kcount[gt];
            int base = 0;
            while (got < 10 && base < kept) {
                int i = base + lane;
                unsigned long long key = (i < kept) ? scand[(size_t)gt * KEEP + i] : ~0ull;
                int p = (int)(unsigned)(key & 0xFFFFFFFFull);
                bool ok = (key != ~0ull) && !((bits[p >> 5] >> (p & 31)) & 1u);
                unsigned long long mask = __ballot(ok);
                int need = 10 - got;
                int pre = __popcll(mask & ((1ull << lane) - 1ull));
                if (ok && pre < need) {
                    out[128 + k * 10 + got + pre] = p;
                    out[1408 + 128 + k * 10 + got + pre] = gt;
                    atomicOr(&bits[p >> 5], 1u << (p & 31));
                }
                int tot = __popcll(mask);
                got += (tot < need) ? tot : need;
                base += 64;
                __syncthreads();
            }
        } else {
            int nc = ccnt[gt]; if (nc > CAP) nc = CAP;
            float lv[10]; int li[10];
#pragma unroll
            for (int q = 0; q < 10; ++q) { lv[q] = -1e30f; li[q] = SENT_I; }
            for (int c = lane; c < nc; c += 64) {
                int2 pr = cpair[(size_t)gt * CAP + c];
                int p = pr.x;
                if ((bits[p >> 5] >> (p & 31)) & 1u) continue;
                float cv = __int_as_float(pr.y); int ci = p;
#pragma unroll
                for (int q = 0; q < 10; ++q) {
                    bool b = (cv > lv[q]) || (cv == lv[q] && ci < li[q]);
                    float tv = b ? lv[q] : cv; int ti = b ? li[q] : ci;
                    if (b) { lv[q] = cv; li[q] = ci; }
                    cv = tv; ci = ti;
                }
            }
#pragma unroll
            for (int q = 0; q < 10; ++q) {
                float mo = lv[0]; int mj = li[0];
#pragma unroll
                for (int off = 1; off < 64; off <<= 1) {
                    float ov = __shfl_xor(mo, off, 64);
                    int oj = __shfl_xor(mj, off, 64);
                    if (ov > mo || (ov == mo && oj < mj)) { mo = ov; mj = oj; }
                }
                bool valid = (mj != SENT_I);
                if (valid && li[0] == mj) {
#pragma unroll
                    for (int t = 0; t < 9; ++t) { lv[t] = lv[t + 1]; li[t] = li[t + 1]; }
                    lv[9] = -1e30f; li[9] = SENT_I;
                }
                if (lane == q) {
                    out[128 + k * 10 + q] = valid ? mj : -1;
                    out[1408 + 128 + k * 10 + q] = valid ? gt : -1;
                    if (valid) atomicOr(&bits[mj >> 5], 1u << (mj & 31));
                }
            }
            got = 10;
            __syncthreads();
        }
        for (int q = got + lane; q < 10; q += 64) {
            out[128 + k * 10 + q] = -1;
            out[1408 + 128 + k * 10 + q] = -1;
        }
        __syncthreads();
    }
}

// ---------- launch ----------

extern "C" void kernel_launch(void* const* d_in, const int* in_sizes, int n_in,
                              void* d_out, int out_size, void* d_ws, size_t ws_size,
                              hipStream_t stream) {
    const float* pc  = (const float*)d_in[0];
    const float* ps  = (const float*)d_in[1];
    const float* cls = (const float*)d_in[2];
    const float* gc  = (const float*)d_in[4];
    const float* gs  = (const float*)d_in[5];
    const int*   lab = (const int*)d_in[6];

    char* ws = (char*)d_ws;
    float*         costT    = (float*)(ws + 0);                  // 33,554,432
    // scand ALIASES costT[0..2MB]: k_prep launched after k_lsa_sparse/k_lsa_dense
    unsigned long long* scand = (unsigned long long*)(ws + 0);   //  2,097,152 (over costT)
    // rowlist ALIASES dense-fallback v (dead before fallback would run)
    int2*          rowlist  = (int2*)(ws + 33554432);            //    135,168 (over v)
    double*        v        = (double*)(ws + 33554432);          //    524,288 (fallback only)
    double*        shortest = (double*)(ws + 34078720);          //    524,288 (fallback only)
    int*           path     = (int*)(ws + 34603008);             //    262,144 (fallback only)
    int*           row4col  = (int*)(ws + 34865152);             //    262,144 (fallback only)
    unsigned char* SC       = (unsigned char*)(ws + 35127296);   //     65,536 (fallback only)
    int*           kcount   = (int*)(ws + 35192832);             //        512
    int*           fullflag = (int*)(ws + 35193344);             //        512
    int*           ccnt     = (int*)(ws + 35193856);             //        512
    unsigned*      cmax     = (unsigned*)(ws + 35194368);        //        512
    int*           order    = (int*)(ws + 35194880);             //        512
    int*           failFlag = (int*)(ws + 35195392);             //        512
    unsigned*      usedbits = (unsigned*)(ws + 35195904);        //      8,192
    int2*          cpair    = (int2*)(ws + 35204096);            // 12,582,912 -> end 47,787,008

    int* out = (int*)d_out;

    hipLaunchKernelGGL(k_init, dim3(1), dim3(128), 0, stream, ccnt, cmax, failFlag);
    hipLaunchKernelGGL(k_cost, dim3(NPRED / 256), dim3(256), 0, stream,
                       pc, ps, cls, gc, gs, lab, costT, ccnt, cmax, cpair);
    hipLaunchKernelGGL(k_sort, dim3(1), dim3(128), 0, stream, cmax, order);
    hipLaunchKernelGGL(k_toprow, dim3(NGT), dim3(256), 0, stream, costT, rowlist);
    hipLaunchKernelGGL(k_lsa_sparse, dim3(1), dim3(64), 0, stream,
                       costT, rowlist, failFlag, usedbits, out);
    hipLaunchKernelGGL(k_lsa_dense, dim3(1), dim3(1024), 0, stream,
                       costT, failFlag, v, shortest, path, row4col, SC, usedbits, out);
    hipLaunchKernelGGL(k_prep, dim3(NGT), dim3(256), 0, stream,
                       cpair, ccnt, scand, kcount, fullflag);
    hipLaunchKernelGGL(k_dyn2, dim3(1), dim3(64), 0, stream,
                       order, kcount, scand, fullflag, ccnt, cpair, usedbits, failFlag, out);
}